// Round 2
// baseline (498.504 us; speedup 1.0000x reference)
//
#include <hip/hip_runtime.h>

#define SEQ 2048
#define HID 2048
#define NH 16
#define HD 128
#define N1 6144   // NH * 3 * HD

typedef __attribute__((ext_vector_type(8))) short short8;
typedef __attribute__((ext_vector_type(8))) __bf16 bf16x8;
typedef __attribute__((ext_vector_type(4))) float f32x4;

__device__ __forceinline__ short f2b(float f) {
  unsigned u = __builtin_bit_cast(unsigned, f);
  unsigned r = (u + 0x7FFFu + ((u >> 16) & 1u)) >> 16;
  return (short)(r & 0xFFFFu);
}
__device__ __forceinline__ float b2f(short s) {
  return __builtin_bit_cast(float, (unsigned)((unsigned short)s) << 16);
}

__device__ __forceinline__ f32x4 mfma16(short8 a, short8 b, f32x4 c) {
  return __builtin_amdgcn_mfma_f32_16x16x32_bf16(
      __builtin_bit_cast(bf16x8, a), __builtin_bit_cast(bf16x8, b), c, 0, 0, 0);
}

// async global->LDS, 16B per lane. LDS dest = wave-uniform base + lane*16.
__device__ __forceinline__ void gload16(const short* g, short* l) {
  __builtin_amdgcn_global_load_lds(
      (const __attribute__((address_space(1))) unsigned int*)g,
      (__attribute__((address_space(3))) unsigned int*)l, 16, 0, 0);
}

// ---------------- cast fp32 -> bf16 bits ----------------
__global__ __launch_bounds__(256) void cast_f32_bf16(const float* __restrict__ in,
                                                     short* __restrict__ out, int n) {
  int i = (blockIdx.x * 256 + threadIdx.x) * 4;
  if (i >= n) return;
  float4 v = *reinterpret_cast<const float4*>(in + i);
  out[i + 0] = f2b(v.x);
  out[i + 1] = f2b(v.y);
  out[i + 2] = f2b(v.z);
  out[i + 3] = f2b(v.w);
}

// ---------------- transpose + cast: in fp32 [R][C] -> out bf16 [C][R] ----------------
__global__ __launch_bounds__(256) void tr_cast(const float* __restrict__ in,
                                               short* __restrict__ out, int R, int C) {
  __shared__ float t[32][33];
  int c0 = blockIdx.x * 32, r0 = blockIdx.y * 32;
  int tx = threadIdx.x, ty = threadIdx.y;  // (32, 8)
#pragma unroll
  for (int i = 0; i < 4; i++) t[ty + i * 8][tx] = in[(r0 + ty + i * 8) * C + c0 + tx];
  __syncthreads();
#pragma unroll
  for (int i = 0; i < 4; i++) out[(c0 + ty + i * 8) * R + r0 + tx] = f2b(t[tx][ty + i * 8]);
}

// ---------------- GEMM (m97 structure): C(MxN) = A(MxK) * Bt(NxK)^T + bias ----------------
// BF16OUT=1 -> bf16 output, else fp32. global_load_lds staging, linear [128][32] LDS.
template <int BF16OUT>
__global__ __launch_bounds__(256) void gemm_bt(const short* __restrict__ A,
                                               const short* __restrict__ Bt,
                                               const float* __restrict__ bias,
                                               void* __restrict__ Cv,
                                               int M, int N, int K) {
  __shared__ __attribute__((aligned(16))) short aT[128 * 32];
  __shared__ __attribute__((aligned(16))) short bT[128 * 32];
  int tid = threadIdx.x;
  int wave = tid >> 6, lane = tid & 63;
  int lhi = lane >> 4, llo = lane & 15;
  int wr = wave >> 1, wc = wave & 1;
  int m0 = blockIdx.y * 128, n0 = blockIdx.x * 128;
  int lr = lane >> 2, lc = (lane & 3) * 8;  // staging: lane's row-in-chunk / col

  f32x4 acc[4][4];
#pragma unroll
  for (int a = 0; a < 4; a++)
#pragma unroll
    for (int b = 0; b < 4; b++) acc[a][b] = (f32x4){0.f, 0.f, 0.f, 0.f};

  const short* Ab = A + (long)m0 * K;
  const short* Bb = Bt + (long)n0 * K;

  for (int k0 = 0; k0 < K; k0 += 32) {
#pragma unroll
    for (int it = 0; it < 2; it++) {
      int c = wave * 2 + it;  // chunk 0..7, 16 rows each
      int row = c * 16 + lr;
      gload16(Ab + (long)row * K + k0 + lc, &aT[c * 512]);
      gload16(Bb + (long)row * K + k0 + lc, &bT[c * 512]);
    }
    __syncthreads();
    short8 af[4], bf[4];
#pragma unroll
    for (int mi = 0; mi < 4; mi++)
      af[mi] = *(const short8*)&aT[(wr * 64 + mi * 16 + llo) * 32 + lhi * 8];
#pragma unroll
    for (int ni = 0; ni < 4; ni++)
      bf[ni] = *(const short8*)&bT[(wc * 64 + ni * 16 + llo) * 32 + lhi * 8];
#pragma unroll
    for (int mi = 0; mi < 4; mi++)
#pragma unroll
      for (int ni = 0; ni < 4; ni++) acc[mi][ni] = mfma16(af[mi], bf[ni], acc[mi][ni]);
    __syncthreads();
  }
#pragma unroll
  for (int mi = 0; mi < 4; mi++)
#pragma unroll
    for (int ni = 0; ni < 4; ni++)
#pragma unroll
      for (int r = 0; r < 4; r++) {
        int row = m0 + wr * 64 + mi * 16 + lhi * 4 + r;
        int col = n0 + wc * 64 + ni * 16 + llo;
        float v = acc[mi][ni][r] + bias[col];
        if (BF16OUT)
          ((short*)Cv)[row * (long)N + col] = f2b(v);
        else
          ((float*)Cv)[row * (long)N + col] = v;
      }
}

// ---------------- RoPE for Q,K (bf16 in/out); 1/sqrt(d) folded into Q ----------------
// qkv bf16 [s][h*384+e]; Qb/Kb bf16 [h][s][d]
__global__ __launch_bounds__(256) void rope_qk(const short* __restrict__ qkv,
                                               short* __restrict__ Qb,
                                               short* __restrict__ Kb) {
  const float INVNORM = 0.08838834764831845f;  // 1/sqrt(128)
  int idx = blockIdx.x * 256 + threadIdx.x;
  int d = idx & 127;
  int sh = idx >> 7;
  int h = sh & 15;
  int s = sh >> 4;
  int base = s * N1 + h * 384;
  float q = b2f(qkv[base + d]);
  float k = b2f(qkv[base + 128 + d]);
  if (d < 32) {
    int i = d & 15;
    float inv_freq = powf(10000.0f, -(float)i * (1.0f / 16.0f));
    float fr = (float)s * inv_freq;
    float c, sn;
    sincosf(fr, &sn, &c);
    if (d < 16) {
      float qo = b2f(qkv[base + d + 16]);
      float ko = b2f(qkv[base + 128 + d + 16]);
      q = q * c - qo * sn;
      k = k * c - ko * sn;
    } else {
      float qo = b2f(qkv[base + d - 16]);
      float ko = b2f(qkv[base + 128 + d - 16]);
      q = q * c + qo * sn;
      k = k * c + ko * sn;
    }
  }
  int o = (h * SEQ + s) * HD + d;
  Qb[o] = f2b(q * INVNORM);
  Kb[o] = f2b(k);
}

// ---------------- V transpose: qkv bf16 [s][h*384+256+d] -> Vt bf16 [h][d][s] ----------------
__global__ __launch_bounds__(256) void v_tr(const short* __restrict__ qkv,
                                            short* __restrict__ Vt) {
  __shared__ short t[32][33];
  int d0 = blockIdx.x * 32, s0 = blockIdx.y * 32, h = blockIdx.z;
  int tx = threadIdx.x, ty = threadIdx.y;  // (32, 8)
#pragma unroll
  for (int i = 0; i < 4; i++)
    t[ty + i * 8][tx] = qkv[(s0 + ty + i * 8) * N1 + h * 384 + 256 + d0 + tx];
  __syncthreads();
#pragma unroll
  for (int i = 0; i < 4; i++)
    Vt[(h * HD + d0 + ty + i * 8) * SEQ + s0 + tx] = t[tx][ty + i * 8];
}

// ---------------- Flash attention (causal), barrier-free ----------------
// grid 512 blocks x 256 thr. Qb [h][s][d] (pre-scaled), Kb [h][s][d], Vt [h][d][s].
// Output attn bf16 [s][h*128+d].
__global__ __launch_bounds__(256) void attn_kernel(const short* __restrict__ Qb,
                                                   const short* __restrict__ Kb,
                                                   const short* __restrict__ Vt,
                                                   short* __restrict__ out) {
  __shared__ __attribute__((aligned(16))) short Pl[4 * 16 * 72];
  int bid = blockIdx.x;
  int sw = (bid & 7) * 64 + (bid >> 3);  // XCD co-location: 2 heads per XCD
  int h = sw >> 5;
  int qt = 31 - (sw & 31);               // heaviest q-tiles dispatch first
  int tid = threadIdx.x;
  int wave = tid >> 6, lane = tid & 63;
  int lhi = lane >> 4, llo = lane & 15;
  int qrow0 = qt * 64 + wave * 16;
  int wbase = wave * 16 * 72;

  // Q fragments (held for whole kernel)
  short8 qf[4];
  const short* Qbase = Qb + (long)(h * SEQ + qrow0 + llo) * HD;
#pragma unroll
  for (int sl = 0; sl < 4; sl++) qf[sl] = *(const short8*)(Qbase + sl * 32 + lhi * 8);

  f32x4 oacc[8];
#pragma unroll
  for (int cb = 0; cb < 8; cb++) oacc[cb] = (f32x4){0.f, 0.f, 0.f, 0.f};
  float m[4], l[4];
#pragma unroll
  for (int r = 0; r < 4; r++) { m[r] = -INFINITY; l[r] = 0.f; }

  const short* Kh = Kb + (long)h * SEQ * HD;
  const short* Vh = Vt + (long)h * HD * SEQ;

  for (int t = 0; t <= qt; t++) {
    // S = Q K^T, K fragments direct from global (L1/L2-resident per head)
    f32x4 sfr[4];
#pragma unroll
    for (int kb = 0; kb < 4; kb++) {
      sfr[kb] = (f32x4){0.f, 0.f, 0.f, 0.f};
      const short* Krow = Kh + (long)(t * 64 + kb * 16 + llo) * HD;
#pragma unroll
      for (int sl = 0; sl < 4; sl++)
        sfr[kb] = mfma16(qf[sl], *(const short8*)(Krow + sl * 32 + lhi * 8), sfr[kb]);
    }

    // causal mask only on the diagonal tile
    if (t == qt) {
#pragma unroll
      for (int kb = 0; kb < 4; kb++)
#pragma unroll
        for (int r = 0; r < 4; r++) {
          int kg = t * 64 + kb * 16 + llo;
          int qg = qrow0 + lhi * 4 + r;
          if (kg > qg) sfr[kb][r] = -1e30f;
        }
    }

    // tile row-max
    float tmax[4];
#pragma unroll
    for (int r = 0; r < 4; r++) tmax[r] = fmaxf(fmaxf(sfr[0][r], sfr[1][r]),
                                                fmaxf(sfr[2][r], sfr[3][r]));
#pragma unroll
    for (int r = 0; r < 4; r++)
#pragma unroll
      for (int msk = 1; msk < 16; msk <<= 1)
        tmax[r] = fmaxf(tmax[r], __shfl_xor(tmax[r], msk));

    float psum[4];
#pragma unroll
    for (int r = 0; r < 4; r++) {
      float mn = fmaxf(m[r], tmax[r]);
      float alpha = __expf(m[r] - mn);
      m[r] = mn;
      l[r] *= alpha;
#pragma unroll
      for (int cb = 0; cb < 8; cb++) oacc[cb][r] *= alpha;
      psum[r] = 0.f;
    }
    // P = exp(S - m) -> per-wave LDS (wave-synchronous, no barrier)
#pragma unroll
    for (int kb = 0; kb < 4; kb++)
#pragma unroll
      for (int r = 0; r < 4; r++) {
        float p = __expf(sfr[kb][r] - m[r]);
        psum[r] += p;
        Pl[wbase + (lhi * 4 + r) * 72 + kb * 16 + llo] = f2b(p);
      }
#pragma unroll
    for (int r = 0; r < 4; r++) {
#pragma unroll
      for (int msk = 1; msk < 16; msk <<= 1) psum[r] += __shfl_xor(psum[r], msk);
      l[r] += psum[r];
    }

    // O += P @ V, V fragments direct from global
#pragma unroll
    for (int ks = 0; ks < 2; ks++) {
      short8 pa = *(const short8*)&Pl[wbase + llo * 72 + ks * 32 + lhi * 8];
#pragma unroll
      for (int cb = 0; cb < 8; cb++) {
        const short* Vrow = Vh + (long)(cb * 16 + llo) * SEQ + t * 64 + ks * 32 + lhi * 8;
        oacc[cb] = mfma16(pa, *(const short8*)Vrow, oacc[cb]);
      }
    }
  }

  // epilogue: normalize and write bf16 [s][h*128+d]
#pragma unroll
  for (int cb = 0; cb < 8; cb++)
#pragma unroll
    for (int r = 0; r < 4; r++) {
      int sg = qrow0 + lhi * 4 + r;
      float val = oacc[cb][r] / l[r];
      out[sg * HID + h * HD + cb * 16 + llo] = f2b(val);
    }
}

extern "C" void kernel_launch(void* const* d_in, const int* in_sizes, int n_in,
                              void* d_out, int out_size, void* d_ws, size_t ws_size,
                              hipStream_t stream) {
  (void)in_sizes; (void)n_in; (void)out_size; (void)ws_size;
  const float* hs = (const float*)d_in[0];
  // d_in[1] = attention_mask (tril causal) — enforced structurally
  const float* w1 = (const float*)d_in[2];
  const float* b1 = (const float*)d_in[3];
  const float* w2 = (const float*)d_in[4];
  const float* b2 = (const float*)d_in[5];
  float* out = (float*)d_out;
  char* ws = (char*)d_ws;

  short* hsb   = (short*)(ws);                 // 2048*2048*2 =  8 MB
  short* w1t   = (short*)(ws + (8L << 20));    // 6144*2048*2 = 24 MB
  short* w2t   = (short*)(ws + (32L << 20));   // 2048*2048*2 =  8 MB
  short* qkvb  = (short*)(ws + (40L << 20));   // 2048*6144*2 = 24 MB
  short* Qb    = (short*)(ws + (64L << 20));   //  8 MB
  short* Kb    = (short*)(ws + (72L << 20));   //  8 MB
  short* Vt    = (short*)(ws + (80L << 20));   //  8 MB
  short* attnb = (short*)(ws + (88L << 20));   //  8 MB (end 96 MB)

  cast_f32_bf16<<<4096, 256, 0, stream>>>(hs, hsb, SEQ * HID);
  tr_cast<<<dim3(N1 / 32, HID / 32), dim3(32, 8), 0, stream>>>(w1, w1t, HID, N1);
  tr_cast<<<dim3(HID / 32, HID / 32), dim3(32, 8), 0, stream>>>(w2, w2t, HID, HID);
  gemm_bt<1><<<dim3(N1 / 128, SEQ / 128), 256, 0, stream>>>(hsb, w1t, b1, qkvb, SEQ, N1, HID);
  rope_qk<<<(SEQ * NH * HD) / 256, 256, 0, stream>>>(qkvb, Qb, Kb);
  v_tr<<<dim3(HD / 32, SEQ / 32, NH), dim3(32, 8), 0, stream>>>(qkvb, Vt);
  attn_kernel<<<512, 256, 0, stream>>>(Qb, Kb, Vt, attnb);
  gemm_bt<0><<<dim3(HID / 128, SEQ / 128), 256, 0, stream>>>(attnb, w2t, b2, out, SEQ, HID, HID);
}

// Round 3
// 350.223 us; speedup vs baseline: 1.4234x; 1.4234x over previous
//
#include <hip/hip_runtime.h>

#define SEQ 2048
#define HID 2048
#define NH 16
#define HD 128
#define N1 6144   // NH * 3 * HD

typedef __attribute__((ext_vector_type(8))) short short8;
typedef __attribute__((ext_vector_type(8))) __bf16 bf16x8;
typedef __attribute__((ext_vector_type(4))) float f32x4;

__device__ __forceinline__ short f2b(float f) {
  unsigned u = __builtin_bit_cast(unsigned, f);
  unsigned r = (u + 0x7FFFu + ((u >> 16) & 1u)) >> 16;
  return (short)(r & 0xFFFFu);
}
__device__ __forceinline__ float b2f(short s) {
  return __builtin_bit_cast(float, (unsigned)((unsigned short)s) << 16);
}

__device__ __forceinline__ f32x4 mfma16(short8 a, short8 b, f32x4 c) {
  return __builtin_amdgcn_mfma_f32_16x16x32_bf16(
      __builtin_bit_cast(bf16x8, a), __builtin_bit_cast(bf16x8, b), c, 0, 0, 0);
}

// async global->LDS, 16B per lane. LDS dest = wave-uniform base + lane*16.
__device__ __forceinline__ void gload16(const short* g, short* l) {
  __builtin_amdgcn_global_load_lds(
      (const __attribute__((address_space(1))) unsigned int*)g,
      (__attribute__((address_space(3))) unsigned int*)l, 16, 0, 0);
}

// ---------------- cast fp32 -> bf16 bits ----------------
__global__ __launch_bounds__(256) void cast_f32_bf16(const float* __restrict__ in,
                                                     short* __restrict__ out, int n) {
  int i = (blockIdx.x * 256 + threadIdx.x) * 8;
  if (i >= n) return;
  float4 a = *reinterpret_cast<const float4*>(in + i);
  float4 b = *reinterpret_cast<const float4*>(in + i + 4);
  short8 o;
  o[0] = f2b(a.x); o[1] = f2b(a.y); o[2] = f2b(a.z); o[3] = f2b(a.w);
  o[4] = f2b(b.x); o[5] = f2b(b.y); o[6] = f2b(b.z); o[7] = f2b(b.w);
  *reinterpret_cast<short8*>(out + i) = o;
}

// ---------------- transpose + cast: in fp32 [R][C] -> out bf16 [C][R] ----------------
__global__ __launch_bounds__(256) void tr_cast(const float* __restrict__ in,
                                               short* __restrict__ out, int R, int C) {
  __shared__ float t[32][33];
  int c0 = blockIdx.x * 32, r0 = blockIdx.y * 32;
  int tx = threadIdx.x, ty = threadIdx.y;  // (32, 8)
#pragma unroll
  for (int i = 0; i < 4; i++) t[ty + i * 8][tx] = in[(r0 + ty + i * 8) * C + c0 + tx];
  __syncthreads();
#pragma unroll
  for (int i = 0; i < 4; i++) out[(c0 + ty + i * 8) * R + r0 + tx] = f2b(t[tx][ty + i * 8]);
}

// ---------------- GEMM (m97 structure): C(MxN) = A(MxK) * Bt(NxK)^T + bias ----------------
template <int BF16OUT>
__global__ __launch_bounds__(256) void gemm_bt(const short* __restrict__ A,
                                               const short* __restrict__ Bt,
                                               const float* __restrict__ bias,
                                               void* __restrict__ Cv,
                                               int M, int N, int K) {
  __shared__ __attribute__((aligned(16))) short aT[128 * 32];
  __shared__ __attribute__((aligned(16))) short bT[128 * 32];
  int tid = threadIdx.x;
  int wave = tid >> 6, lane = tid & 63;
  int lhi = lane >> 4, llo = lane & 15;
  int wr = wave >> 1, wc = wave & 1;
  int m0 = blockIdx.y * 128, n0 = blockIdx.x * 128;
  int lr = lane >> 2, lc = (lane & 3) * 8;  // staging: lane's row-in-chunk / col

  f32x4 acc[4][4];
#pragma unroll
  for (int a = 0; a < 4; a++)
#pragma unroll
    for (int b = 0; b < 4; b++) acc[a][b] = (f32x4){0.f, 0.f, 0.f, 0.f};

  const short* Ab = A + (long)m0 * K;
  const short* Bb = Bt + (long)n0 * K;

  for (int k0 = 0; k0 < K; k0 += 32) {
#pragma unroll
    for (int it = 0; it < 2; it++) {
      int c = wave * 2 + it;  // chunk 0..7, 16 rows each
      int row = c * 16 + lr;
      gload16(Ab + (long)row * K + k0 + lc, &aT[c * 512]);
      gload16(Bb + (long)row * K + k0 + lc, &bT[c * 512]);
    }
    __syncthreads();
    short8 af[4], bf[4];
#pragma unroll
    for (int mi = 0; mi < 4; mi++)
      af[mi] = *(const short8*)&aT[(wr * 64 + mi * 16 + llo) * 32 + lhi * 8];
#pragma unroll
    for (int ni = 0; ni < 4; ni++)
      bf[ni] = *(const short8*)&bT[(wc * 64 + ni * 16 + llo) * 32 + lhi * 8];
#pragma unroll
    for (int mi = 0; mi < 4; mi++)
#pragma unroll
      for (int ni = 0; ni < 4; ni++) acc[mi][ni] = mfma16(af[mi], bf[ni], acc[mi][ni]);
    __syncthreads();
  }
#pragma unroll
  for (int mi = 0; mi < 4; mi++)
#pragma unroll
    for (int ni = 0; ni < 4; ni++)
#pragma unroll
      for (int r = 0; r < 4; r++) {
        int row = m0 + wr * 64 + mi * 16 + lhi * 4 + r;
        int col = n0 + wc * 64 + ni * 16 + llo;
        float v = acc[mi][ni][r] + bias[col];
        if (BF16OUT)
          ((short*)Cv)[row * (long)N + col] = f2b(v);
        else
          ((float*)Cv)[row * (long)N + col] = v;
      }
}

// ---------------- RoPE for Q,K (bf16 in/out); 1/sqrt(d) folded into Q ----------------
__global__ __launch_bounds__(256) void rope_qk(const short* __restrict__ qkv,
                                               short* __restrict__ Qb,
                                               short* __restrict__ Kb) {
  const float INVNORM = 0.08838834764831845f;  // 1/sqrt(128)
  int idx = blockIdx.x * 256 + threadIdx.x;
  int d = idx & 127;
  int sh = idx >> 7;
  int h = sh & 15;
  int s = sh >> 4;
  int base = s * N1 + h * 384;
  float q = b2f(qkv[base + d]);
  float k = b2f(qkv[base + 128 + d]);
  if (d < 32) {
    int i = d & 15;
    // 10000^(-i/16) == 2^(-i*log2(10000)/16)
    float inv_freq = exp2f(-(float)i * 0.8304820237218407f);
    float fr = (float)s * inv_freq;
    float c, sn;
    sincosf(fr, &sn, &c);
    if (d < 16) {
      float qo = b2f(qkv[base + d + 16]);
      float ko = b2f(qkv[base + 128 + d + 16]);
      q = q * c - qo * sn;
      k = k * c - ko * sn;
    } else {
      float qo = b2f(qkv[base + d - 16]);
      float ko = b2f(qkv[base + 128 + d - 16]);
      q = q * c + qo * sn;
      k = k * c + ko * sn;
    }
  }
  int o = (h * SEQ + s) * HD + d;
  Qb[o] = f2b(q * INVNORM);
  Kb[o] = f2b(k);
}

// ---------------- V transpose: qkv bf16 [s][h*384+256+d] -> Vt bf16 [h][d][s] ----------------
__global__ __launch_bounds__(256) void v_tr(const short* __restrict__ qkv,
                                            short* __restrict__ Vt) {
  __shared__ short t[32][33];
  int d0 = blockIdx.x * 32, s0 = blockIdx.y * 32, h = blockIdx.z;
  int tx = threadIdx.x, ty = threadIdx.y;  // (32, 8)
#pragma unroll
  for (int i = 0; i < 4; i++)
    t[ty + i * 8][tx] = qkv[(s0 + ty + i * 8) * N1 + h * 384 + 256 + d0 + tx];
  __syncthreads();
#pragma unroll
  for (int i = 0; i < 4; i++)
    Vt[(h * HD + d0 + ty + i * 8) * SEQ + s0 + tx] = t[tx][ty + i * 8];
}

// ---------------- Flash attention (causal), 2-phase double-buffered LDS ----------------
// grid 512 x 256 thr. Qb [h][s][d] (pre-scaled), Kb [h][s][d], Vt [h][d][s].
// Output attn bf16 [s][h*128+d].
__global__ __launch_bounds__(256) void attn_kernel(const short* __restrict__ Qb,
                                                   const short* __restrict__ Kb,
                                                   const short* __restrict__ Vt,
                                                   short* __restrict__ out) {
  __shared__ __attribute__((aligned(16))) short Kl[2][64 * 136];
  __shared__ __attribute__((aligned(16))) short Vl[2][128 * 72];
  __shared__ __attribute__((aligned(16))) short Pl[4][16 * 72];
  int bid = blockIdx.x;
  int sw = (bid & 7) * 64 + (bid >> 3);  // XCD co-location: 2 heads per XCD
  int h = sw >> 5;
  int qt = 31 - (sw & 31);               // heaviest q-tiles dispatch first
  int tid = threadIdx.x;
  int wave = tid >> 6, lane = tid & 63;
  int lhi = lane >> 4, llo = lane & 15;
  int qrow0 = qt * 64 + wave * 16;

  const short* Kh = Kb + (long)h * SEQ * HD;
  const short* Vh = Vt + (long)h * HD * SEQ;

  // Q fragments (held for whole kernel)
  short8 qf[4];
  const short* Qbase = Qb + (long)(h * SEQ + qrow0 + llo) * HD;
#pragma unroll
  for (int sl = 0; sl < 4; sl++) qf[sl] = *(const short8*)(Qbase + sl * 32 + lhi * 8);

  f32x4 oacc[8];
#pragma unroll
  for (int cb = 0; cb < 8; cb++) oacc[cb] = (f32x4){0.f, 0.f, 0.f, 0.f};
  float m[4], l[4];
#pragma unroll
  for (int r = 0; r < 4; r++) { m[r] = -INFINITY; l[r] = 0.f; }

  // staging registers (T14: issue early, write late)
  short8 kreg[4], vreg[4];
  // K tile: 64 rows x 128 shorts = 1024 segs of 8 shorts; seg s: row=s>>4, c8=s&15
  // V tile: 128 rows x 64 shorts = 1024 segs of 8 shorts; seg s: row=s>>3, c8=s&7
#define ISSUE_KV(T)                                                                   \
  {                                                                                   \
    _Pragma("unroll") for (int i = 0; i < 4; i++) {                                   \
      int s = tid + i * 256;                                                          \
      kreg[i] = *(const short8*)(Kh + (long)((T) * 64 + (s >> 4)) * HD + (s & 15) * 8); \
      vreg[i] = *(const short8*)(Vh + (long)(s >> 3) * SEQ + (T) * 64 + (s & 7) * 8); \
    }                                                                                 \
  }
#define WRITE_KV(BUF)                                                        \
  {                                                                          \
    _Pragma("unroll") for (int i = 0; i < 4; i++) {                          \
      int s = tid + i * 256;                                                 \
      *(short8*)&Kl[BUF][(s >> 4) * 136 + (s & 15) * 8] = kreg[i];           \
      *(short8*)&Vl[BUF][(s >> 3) * 72 + (s & 7) * 8] = vreg[i];             \
    }                                                                        \
  }

  // prologue: stage tile 0 into buf 0
  ISSUE_KV(0);
  WRITE_KV(0);
  __syncthreads();

  int cur = 0;
  for (int t = 0; t <= qt; t++) {
    bool pre = (t < qt);
    if (pre) ISSUE_KV(t + 1);  // loads in flight during compute

    // ---- S = Q K^T from Kl[cur] ----
    f32x4 sfr[4];
#pragma unroll
    for (int kb = 0; kb < 4; kb++) {
      sfr[kb] = (f32x4){0.f, 0.f, 0.f, 0.f};
#pragma unroll
      for (int sl = 0; sl < 4; sl++) {
        short8 bk = *(const short8*)&Kl[cur][(kb * 16 + llo) * 136 + sl * 32 + lhi * 8];
        sfr[kb] = mfma16(qf[sl], bk, sfr[kb]);
      }
    }

    // causal mask only on the diagonal tile
    if (t == qt) {
#pragma unroll
      for (int kb = 0; kb < 4; kb++)
#pragma unroll
        for (int r = 0; r < 4; r++) {
          int kg = t * 64 + kb * 16 + llo;
          int qg = qrow0 + lhi * 4 + r;
          if (kg > qg) sfr[kb][r] = -1e30f;
        }
    }

    // ---- online softmax ----
    float tmax[4];
#pragma unroll
    for (int r = 0; r < 4; r++)
      tmax[r] = fmaxf(fmaxf(sfr[0][r], sfr[1][r]), fmaxf(sfr[2][r], sfr[3][r]));
#pragma unroll
    for (int r = 0; r < 4; r++)
#pragma unroll
      for (int msk = 1; msk < 16; msk <<= 1)
        tmax[r] = fmaxf(tmax[r], __shfl_xor(tmax[r], msk));

    // T13 defer-max: skip rescale if max didn't grow by > 8 anywhere
    float grow = fmaxf(fmaxf(tmax[0] - m[0], tmax[1] - m[1]),
                       fmaxf(tmax[2] - m[2], tmax[3] - m[3]));
    if (!__all(grow <= 8.0f)) {
#pragma unroll
      for (int r = 0; r < 4; r++) {
        float mn = fmaxf(m[r], tmax[r]);
        float alpha = __expf(m[r] - mn);
        m[r] = mn;
        l[r] *= alpha;
#pragma unroll
        for (int cb = 0; cb < 8; cb++) oacc[cb][r] *= alpha;
      }
    }

    float psum[4];
#pragma unroll
    for (int r = 0; r < 4; r++) psum[r] = 0.f;
#pragma unroll
    for (int kb = 0; kb < 4; kb++)
#pragma unroll
      for (int r = 0; r < 4; r++) {
        float p = __expf(sfr[kb][r] - m[r]);
        psum[r] += p;
        Pl[wave][(lhi * 4 + r) * 72 + kb * 16 + llo] = f2b(p);
      }
#pragma unroll
    for (int r = 0; r < 4; r++) {
#pragma unroll
      for (int msk = 1; msk < 16; msk <<= 1) psum[r] += __shfl_xor(psum[r], msk);
      l[r] += psum[r];
    }

    // ---- O += P @ V from Vl[cur] ----
#pragma unroll
    for (int ks = 0; ks < 2; ks++) {
      short8 pa = *(const short8*)&Pl[wave][llo * 72 + ks * 32 + lhi * 8];
#pragma unroll
      for (int cb = 0; cb < 8; cb++) {
        short8 bv = *(const short8*)&Vl[cur][(cb * 16 + llo) * 72 + ks * 32 + lhi * 8];
        oacc[cb] = mfma16(pa, bv, oacc[cb]);
      }
    }

    // ---- write prefetched tile into the other buffer; one barrier per tile ----
    if (pre) {
      WRITE_KV(cur ^ 1);
      __syncthreads();
      cur ^= 1;
    }
  }
#undef ISSUE_KV
#undef WRITE_KV

  // epilogue: normalize and write bf16 [s][h*128+d]
#pragma unroll
  for (int cb = 0; cb < 8; cb++)
#pragma unroll
    for (int r = 0; r < 4; r++) {
      int sg = qrow0 + lhi * 4 + r;
      float val = oacc[cb][r] / l[r];
      out[sg * HID + h * HD + cb * 16 + llo] = f2b(val);
    }
}

extern "C" void kernel_launch(void* const* d_in, const int* in_sizes, int n_in,
                              void* d_out, int out_size, void* d_ws, size_t ws_size,
                              hipStream_t stream) {
  (void)in_sizes; (void)n_in; (void)out_size; (void)ws_size;
  const float* hs = (const float*)d_in[0];
  // d_in[1] = attention_mask (tril causal) — enforced structurally
  const float* w1 = (const float*)d_in[2];
  const float* b1 = (const float*)d_in[3];
  const float* w2 = (const float*)d_in[4];
  const float* b2 = (const float*)d_in[5];
  float* out = (float*)d_out;
  char* ws = (char*)d_ws;

  short* hsb   = (short*)(ws);                 // 2048*2048*2 =  8 MB
  short* w1t   = (short*)(ws + (8L << 20));    // 6144*2048*2 = 24 MB
  short* w2t   = (short*)(ws + (32L << 20));   // 2048*2048*2 =  8 MB
  short* qkvb  = (short*)(ws + (40L << 20));   // 2048*6144*2 = 24 MB
  short* Qb    = (short*)(ws + (64L << 20));   //  8 MB
  short* Kb    = (short*)(ws + (72L << 20));   //  8 MB
  short* Vt    = (short*)(ws + (80L << 20));   //  8 MB
  short* attnb = (short*)(ws + (88L << 20));   //  8 MB (end 96 MB)

  cast_f32_bf16<<<(SEQ * HID) / 2048, 256, 0, stream>>>(hs, hsb, SEQ * HID);
  tr_cast<<<dim3(N1 / 32, HID / 32), dim3(32, 8), 0, stream>>>(w1, w1t, HID, N1);
  tr_cast<<<dim3(HID / 32, HID / 32), dim3(32, 8), 0, stream>>>(w2, w2t, HID, HID);
  gemm_bt<1><<<dim3(N1 / 128, SEQ / 128), 256, 0, stream>>>(hsb, w1t, b1, qkvb, SEQ, N1, HID);
  rope_qk<<<(SEQ * NH * HD) / 256, 256, 0, stream>>>(qkvb, Qb, Kb);
  v_tr<<<dim3(HD / 32, SEQ / 32, NH), dim3(32, 8), 0, stream>>>(qkvb, Vt);
  attn_kernel<<<512, 256, 0, stream>>>(Qb, Kb, Vt, attnb);
  gemm_bt<0><<<dim3(HID / 128, SEQ / 128), 256, 0, stream>>>(attnb, w2t, b2, out, SEQ, HID, HID);
}

// Round 4
// 342.678 us; speedup vs baseline: 1.4547x; 1.0220x over previous
//
#include <hip/hip_runtime.h>

#define SEQ 2048
#define HID 2048
#define NH 16
#define HD 128
#define N1 6144   // NH * 3 * HD

typedef __attribute__((ext_vector_type(8))) short short8;
typedef __attribute__((ext_vector_type(8))) __bf16 bf16x8;
typedef __attribute__((ext_vector_type(4))) float f32x4;

__device__ __forceinline__ short f2b(float f) {
  unsigned u = __builtin_bit_cast(unsigned, f);
  unsigned r = (u + 0x7FFFu + ((u >> 16) & 1u)) >> 16;
  return (short)(r & 0xFFFFu);
}
__device__ __forceinline__ float b2f(short s) {
  return __builtin_bit_cast(float, (unsigned)((unsigned short)s) << 16);
}

__device__ __forceinline__ f32x4 mfma16(short8 a, short8 b, f32x4 c) {
  return __builtin_amdgcn_mfma_f32_16x16x32_bf16(
      __builtin_bit_cast(bf16x8, a), __builtin_bit_cast(bf16x8, b), c, 0, 0, 0);
}

// async global->LDS, 16B per lane. LDS dest = wave-uniform base + lane*16.
__device__ __forceinline__ void gload16(const short* g, short* l) {
  __builtin_amdgcn_global_load_lds(
      (const __attribute__((address_space(1))) unsigned int*)g,
      (__attribute__((address_space(3))) unsigned int*)l, 16, 0, 0);
}

// ---------------- cast fp32 -> bf16 bits ----------------
__global__ __launch_bounds__(256) void cast_f32_bf16(const float* __restrict__ in,
                                                     short* __restrict__ out, int n) {
  int i = (blockIdx.x * 256 + threadIdx.x) * 8;
  if (i >= n) return;
  float4 a = *reinterpret_cast<const float4*>(in + i);
  float4 b = *reinterpret_cast<const float4*>(in + i + 4);
  short8 o;
  o[0] = f2b(a.x); o[1] = f2b(a.y); o[2] = f2b(a.z); o[3] = f2b(a.w);
  o[4] = f2b(b.x); o[5] = f2b(b.y); o[6] = f2b(b.z); o[7] = f2b(b.w);
  *reinterpret_cast<short8*>(out + i) = o;
}

// ---------------- transpose + cast: in fp32 [R][C] -> out bf16 [C][R] ----------------
__global__ __launch_bounds__(256) void tr_cast(const float* __restrict__ in,
                                               short* __restrict__ out, int R, int C) {
  __shared__ float t[32][33];
  int c0 = blockIdx.x * 32, r0 = blockIdx.y * 32;
  int tx = threadIdx.x, ty = threadIdx.y;  // (32, 8)
#pragma unroll
  for (int i = 0; i < 4; i++) t[ty + i * 8][tx] = in[(r0 + ty + i * 8) * C + c0 + tx];
  __syncthreads();
#pragma unroll
  for (int i = 0; i < 4; i++) out[(c0 + ty + i * 8) * R + r0 + tx] = f2b(t[tx][ty + i * 8]);
}

// ---------------- GEMM (m97 structure): C(MxN) = A(MxK) * Bt(NxK)^T + bias ----------------
template <int BF16OUT>
__global__ __launch_bounds__(256) void gemm_bt(const short* __restrict__ A,
                                               const short* __restrict__ Bt,
                                               const float* __restrict__ bias,
                                               void* __restrict__ Cv,
                                               int M, int N, int K) {
  __shared__ __attribute__((aligned(16))) short aT[128 * 32];
  __shared__ __attribute__((aligned(16))) short bT[128 * 32];
  int tid = threadIdx.x;
  int wave = tid >> 6, lane = tid & 63;
  int lhi = lane >> 4, llo = lane & 15;
  int wr = wave >> 1, wc = wave & 1;
  int m0 = blockIdx.y * 128, n0 = blockIdx.x * 128;
  int lr = lane >> 2, lc = (lane & 3) * 8;  // staging: lane's row-in-chunk / col

  f32x4 acc[4][4];
#pragma unroll
  for (int a = 0; a < 4; a++)
#pragma unroll
    for (int b = 0; b < 4; b++) acc[a][b] = (f32x4){0.f, 0.f, 0.f, 0.f};

  const short* Ab = A + (long)m0 * K;
  const short* Bb = Bt + (long)n0 * K;

  for (int k0 = 0; k0 < K; k0 += 32) {
#pragma unroll
    for (int it = 0; it < 2; it++) {
      int c = wave * 2 + it;  // chunk 0..7, 16 rows each
      int row = c * 16 + lr;
      gload16(Ab + (long)row * K + k0 + lc, &aT[c * 512]);
      gload16(Bb + (long)row * K + k0 + lc, &bT[c * 512]);
    }
    __syncthreads();
    short8 af[4], bf[4];
#pragma unroll
    for (int mi = 0; mi < 4; mi++)
      af[mi] = *(const short8*)&aT[(wr * 64 + mi * 16 + llo) * 32 + lhi * 8];
#pragma unroll
    for (int ni = 0; ni < 4; ni++)
      bf[ni] = *(const short8*)&bT[(wc * 64 + ni * 16 + llo) * 32 + lhi * 8];
#pragma unroll
    for (int mi = 0; mi < 4; mi++)
#pragma unroll
      for (int ni = 0; ni < 4; ni++) acc[mi][ni] = mfma16(af[mi], bf[ni], acc[mi][ni]);
    __syncthreads();
  }
#pragma unroll
  for (int mi = 0; mi < 4; mi++)
#pragma unroll
    for (int ni = 0; ni < 4; ni++)
#pragma unroll
      for (int r = 0; r < 4; r++) {
        int row = m0 + wr * 64 + mi * 16 + lhi * 4 + r;
        int col = n0 + wc * 64 + ni * 16 + llo;
        float v = acc[mi][ni][r] + bias[col];
        if (BF16OUT)
          ((short*)Cv)[row * (long)N + col] = f2b(v);
        else
          ((float*)Cv)[row * (long)N + col] = v;
      }
}

// ---------------- Fused RoPE(Q,K) + V transpose ----------------
// qkv bf16 [s][h*384+e] -> Qb/Kb bf16 [h][s][d] (Q pre-scaled), Vt bf16 [h][d][s]
// grid (HD/32, SEQ/32, NH), block (32,8)
__global__ __launch_bounds__(256) void rope_v(const short* __restrict__ qkv,
                                              short* __restrict__ Qb,
                                              short* __restrict__ Kb,
                                              short* __restrict__ Vt) {
  __shared__ short t[32][33];
  const float INVNORM = 0.08838834764831845f;  // 1/sqrt(128)
  int d0 = blockIdx.x * 32, s0 = blockIdx.y * 32, h = blockIdx.z;
  int tx = threadIdx.x, ty = threadIdx.y;  // (32, 8)
#pragma unroll
  for (int i = 0; i < 4; i++) {
    int s = s0 + ty + i * 8;
    int base = s * N1 + h * 384;
    // V into LDS for transpose
    t[ty + i * 8][tx] = qkv[base + 256 + d0 + tx];
    // Q, K with rotary on d<32 (d0==0 block only; partner d^16 via shfl)
    float q = b2f(qkv[base + d0 + tx]);
    float k = b2f(qkv[base + 128 + d0 + tx]);
    if (d0 == 0) {
      float qo = __shfl_xor(q, 16);
      float ko = __shfl_xor(k, 16);
      int ii = tx & 15;
      // 10000^(-ii/16) == 2^(-ii*log2(10000)/16)
      float inv_freq = exp2f(-(float)ii * 0.8304820237218407f);
      float fr = (float)s * inv_freq;
      float c, sn;
      sincosf(fr, &sn, &c);
      float sgn = (tx < 16) ? -1.f : 1.f;
      q = q * c + sgn * qo * sn;
      k = k * c + sgn * ko * sn;
    }
    int o = (h * SEQ + s) * HD + d0 + tx;
    Qb[o] = f2b(q * INVNORM);
    Kb[o] = f2b(k);
  }
  __syncthreads();
#pragma unroll
  for (int i = 0; i < 4; i++)
    Vt[(h * HD + d0 + ty + i * 8) * SEQ + s0 + tx] = t[tx][ty + i * 8];
}

// ---------------- Flash attention, split-K (chunks of <=8 KV-tiles) ----------------
// grid 1280 x 256. Qb [h][s][d] (pre-scaled), Kb [h][s][d], Vt [h][d][s].
// Writes unnormalized partial O (bf16) + per-row (m,l) fp32.
// Chunk list per head: for qt in 0..31, nc = (qt>>3)+1 chunks of <=8 tiles. 80/head.
__global__ __launch_bounds__(256) void attn_kernel(const short* __restrict__ Qb,
                                                   const short* __restrict__ Kb,
                                                   const short* __restrict__ Vt,
                                                   short* __restrict__ Opart,
                                                   float* __restrict__ ml) {
  __shared__ __attribute__((aligned(16))) short Kl[2][64 * 136];
  __shared__ __attribute__((aligned(16))) short Vl[2][128 * 72];
  __shared__ __attribute__((aligned(16))) short Pl[4][16 * 72];
  int bid = blockIdx.x;
  int x = bid & 7, j = bid >> 3;          // XCD co-location: 2 heads per XCD
  int h = (x << 1) | (j >= 80 ? 1 : 0);
  int c = (j >= 80 ? j - 80 : j);
  c = 79 - c;                              // heaviest chunks (qt=31) dispatch first
  int qt = 0;
  for (; qt < 32; qt++) {
    int nc = (qt >> 3) + 1;
    if (c < nc) break;
    c -= nc;
  }
  int ci = c;
  int kt0 = ci * 8;
  int kt1 = min(qt + 1, kt0 + 8);
  int slot = ((h * 32 + qt) << 2) + ci;

  int tid = threadIdx.x;
  int wave = tid >> 6, lane = tid & 63;
  int lhi = lane >> 4, llo = lane & 15;
  int qrow0 = qt * 64 + wave * 16;

  const short* Kh = Kb + (long)h * SEQ * HD;
  const short* Vh = Vt + (long)h * HD * SEQ;

  // Q fragments
  short8 qf[4];
  const short* Qbase = Qb + (long)(h * SEQ + qrow0 + llo) * HD;
#pragma unroll
  for (int sl = 0; sl < 4; sl++) qf[sl] = *(const short8*)(Qbase + sl * 32 + lhi * 8);

  f32x4 oacc[8];
#pragma unroll
  for (int cb = 0; cb < 8; cb++) oacc[cb] = (f32x4){0.f, 0.f, 0.f, 0.f};
  float m[4], l[4];
#pragma unroll
  for (int r = 0; r < 4; r++) { m[r] = -INFINITY; l[r] = 0.f; }

  // staging registers (T14: issue early, write late)
  short8 kreg[4], vreg[4];
#define ISSUE_KV(T)                                                                     \
  {                                                                                     \
    _Pragma("unroll") for (int i = 0; i < 4; i++) {                                     \
      int s = tid + i * 256;                                                            \
      kreg[i] = *(const short8*)(Kh + (long)((T) * 64 + (s >> 4)) * HD + (s & 15) * 8); \
      vreg[i] = *(const short8*)(Vh + (long)(s >> 3) * SEQ + (T) * 64 + (s & 7) * 8);   \
    }                                                                                   \
  }
#define WRITE_KV(BUF)                                                        \
  {                                                                          \
    _Pragma("unroll") for (int i = 0; i < 4; i++) {                          \
      int s = tid + i * 256;                                                 \
      *(short8*)&Kl[BUF][(s >> 4) * 136 + (s & 15) * 8] = kreg[i];           \
      *(short8*)&Vl[BUF][(s >> 3) * 72 + (s & 7) * 8] = vreg[i];             \
    }                                                                        \
  }

  ISSUE_KV(kt0);
  WRITE_KV(0);
  __syncthreads();

  int cur = 0;
  for (int t = kt0; t < kt1; t++) {
    bool pre = (t + 1 < kt1);
    if (pre) ISSUE_KV(t + 1);

    // ---- S = Q K^T from Kl[cur] ----
    f32x4 sfr[4];
#pragma unroll
    for (int kb = 0; kb < 4; kb++) {
      sfr[kb] = (f32x4){0.f, 0.f, 0.f, 0.f};
#pragma unroll
      for (int sl = 0; sl < 4; sl++) {
        short8 bk = *(const short8*)&Kl[cur][(kb * 16 + llo) * 136 + sl * 32 + lhi * 8];
        sfr[kb] = mfma16(qf[sl], bk, sfr[kb]);
      }
    }

    // causal mask only on the diagonal tile
    if (t == qt) {
#pragma unroll
      for (int kb = 0; kb < 4; kb++)
#pragma unroll
        for (int r = 0; r < 4; r++) {
          int kg = t * 64 + kb * 16 + llo;
          int qg = qrow0 + lhi * 4 + r;
          if (kg > qg) sfr[kb][r] = -1e30f;
        }
    }

    // ---- online softmax ----
    float tmax[4];
#pragma unroll
    for (int r = 0; r < 4; r++)
      tmax[r] = fmaxf(fmaxf(sfr[0][r], sfr[1][r]), fmaxf(sfr[2][r], sfr[3][r]));
#pragma unroll
    for (int r = 0; r < 4; r++)
#pragma unroll
      for (int msk = 1; msk < 16; msk <<= 1)
        tmax[r] = fmaxf(tmax[r], __shfl_xor(tmax[r], msk));

    // T13 defer-max
    float grow = fmaxf(fmaxf(tmax[0] - m[0], tmax[1] - m[1]),
                       fmaxf(tmax[2] - m[2], tmax[3] - m[3]));
    if (!__all(grow <= 8.0f)) {
#pragma unroll
      for (int r = 0; r < 4; r++) {
        float mn = fmaxf(m[r], tmax[r]);
        float alpha = __expf(m[r] - mn);
        m[r] = mn;
        l[r] *= alpha;
#pragma unroll
        for (int cb = 0; cb < 8; cb++) oacc[cb][r] *= alpha;
      }
    }

    float psum[4];
#pragma unroll
    for (int r = 0; r < 4; r++) psum[r] = 0.f;
#pragma unroll
    for (int kb = 0; kb < 4; kb++)
#pragma unroll
      for (int r = 0; r < 4; r++) {
        float p = __expf(sfr[kb][r] - m[r]);
        psum[r] += p;
        Pl[wave][(lhi * 4 + r) * 72 + kb * 16 + llo] = f2b(p);
      }
#pragma unroll
    for (int r = 0; r < 4; r++) {
#pragma unroll
      for (int msk = 1; msk < 16; msk <<= 1) psum[r] += __shfl_xor(psum[r], msk);
      l[r] += psum[r];
    }

    // ---- O += P @ V from Vl[cur] ----
#pragma unroll
    for (int ks = 0; ks < 2; ks++) {
      short8 pa = *(const short8*)&Pl[wave][llo * 72 + ks * 32 + lhi * 8];
#pragma unroll
      for (int cb = 0; cb < 8; cb++) {
        short8 bv = *(const short8*)&Vl[cur][(cb * 16 + llo) * 72 + ks * 32 + lhi * 8];
        oacc[cb] = mfma16(pa, bv, oacc[cb]);
      }
    }

    if (pre) {
      WRITE_KV(cur ^ 1);
      __syncthreads();
      cur ^= 1;
    }
  }
#undef ISSUE_KV
#undef WRITE_KV

  // epilogue: write unnormalized partial O (bf16) + m,l (fp32)
  long obase = (long)slot * (64 * 128);
#pragma unroll
  for (int cb = 0; cb < 8; cb++)
#pragma unroll
    for (int r = 0; r < 4; r++) {
      int row = wave * 16 + lhi * 4 + r;
      Opart[obase + row * 128 + cb * 16 + llo] = f2b(oacc[cb][r]);
    }
  if (llo == 0) {
#pragma unroll
    for (int r = 0; r < 4; r++) {
      int row = wave * 16 + lhi * 4 + r;
      ml[slot * 128 + row * 2 + 0] = m[r];
      ml[slot * 128 + row * 2 + 1] = l[r];
    }
  }
}

// ---------------- merge split-K partials -> attn bf16 [s][h*128+d] ----------------
// grid (32, 16) = (qt, h), block 256
__global__ __launch_bounds__(256) void attn_merge(const short* __restrict__ Opart,
                                                  const float* __restrict__ ml,
                                                  short* __restrict__ out) {
  int qt = blockIdx.x, h = blockIdx.y;
  int nc = (qt >> 3) + 1;
  int tid = threadIdx.x;
  int row = tid >> 2;          // 0..63
  int c0 = (tid & 3) * 32;     // col base, 32 cols/thread
  int slot0 = (h * 32 + qt) << 2;

  float mm[4], ll[4], alpha[4];
  float M = -INFINITY;
  for (int i = 0; i < nc; i++) {
    mm[i] = ml[(slot0 + i) * 128 + row * 2 + 0];
    ll[i] = ml[(slot0 + i) * 128 + row * 2 + 1];
    M = fmaxf(M, mm[i]);
  }
  float L = 0.f;
  for (int i = 0; i < nc; i++) {
    alpha[i] = __expf(mm[i] - M);
    L += ll[i] * alpha[i];
  }
  float invL = 1.0f / L;

  int s = qt * 64 + row;
#pragma unroll
  for (int cc = 0; cc < 32; cc += 8) {
    float acc[8];
#pragma unroll
    for (int jj = 0; jj < 8; jj++) acc[jj] = 0.f;
    for (int i = 0; i < nc; i++) {
      short8 v = *(const short8*)&Opart[(long)(slot0 + i) * 8192 + row * 128 + c0 + cc];
#pragma unroll
      for (int jj = 0; jj < 8; jj++) acc[jj] += alpha[i] * b2f(v[jj]);
    }
    short8 o;
#pragma unroll
    for (int jj = 0; jj < 8; jj++) o[jj] = f2b(acc[jj] * invL);
    *(short8*)&out[s * HID + h * HD + c0 + cc] = o;
  }
}

extern "C" void kernel_launch(void* const* d_in, const int* in_sizes, int n_in,
                              void* d_out, int out_size, void* d_ws, size_t ws_size,
                              hipStream_t stream) {
  (void)in_sizes; (void)n_in; (void)out_size; (void)ws_size;
  const float* hs = (const float*)d_in[0];
  // d_in[1] = attention_mask (tril causal) — enforced structurally
  const float* w1 = (const float*)d_in[2];
  const float* b1 = (const float*)d_in[3];
  const float* w2 = (const float*)d_in[4];
  const float* b2 = (const float*)d_in[5];
  float* out = (float*)d_out;
  char* ws = (char*)d_ws;

  // Opart (32MB) overlays hsb+w1t — both dead after the QKV GEMM (stream-ordered).
  short* hsb   = (short*)(ws);                 // [0,8) MB
  short* w1t   = (short*)(ws + (8L << 20));    // [8,32) MB
  short* Opart = (short*)(ws);                 // [0,32) MB (after gemm1)
  short* w2t   = (short*)(ws + (32L << 20));   // [32,40) MB
  short* qkvb  = (short*)(ws + (40L << 20));   // [40,64) MB
  short* Qb    = (short*)(ws + (64L << 20));   // [64,72) MB
  short* Kb    = (short*)(ws + (72L << 20));   // [72,80) MB
  short* Vt    = (short*)(ws + (80L << 20));   // [80,88) MB
  short* attnb = (short*)(ws + (88L << 20));   // [88,96) MB
  float* ml    = (float*)(ws + (96L << 20));   // [96,97) MB

  cast_f32_bf16<<<(SEQ * HID) / 2048, 256, 0, stream>>>(hs, hsb, SEQ * HID);
  tr_cast<<<dim3(N1 / 32, HID / 32), dim3(32, 8), 0, stream>>>(w1, w1t, HID, N1);
  tr_cast<<<dim3(HID / 32, HID / 32), dim3(32, 8), 0, stream>>>(w2, w2t, HID, HID);
  gemm_bt<1><<<dim3(N1 / 128, SEQ / 128), 256, 0, stream>>>(hsb, w1t, b1, qkvb, SEQ, N1, HID);
  rope_v<<<dim3(HD / 32, SEQ / 32, NH), dim3(32, 8), 0, stream>>>(qkvb, Qb, Kb, Vt);
  attn_kernel<<<1280, 256, 0, stream>>>(Qb, Kb, Vt, Opart, ml);
  attn_merge<<<dim3(32, 16), 256, 0, stream>>>(Opart, ml, attnb);
  gemm_bt<0><<<dim3(HID / 128, SEQ / 128), 256, 0, stream>>>(attnb, w2t, b2, out, SEQ, HID, HID);
}

// Round 5
// 332.613 us; speedup vs baseline: 1.4988x; 1.0303x over previous
//
#include <hip/hip_runtime.h>

#define SEQ 2048
#define HID 2048
#define NH 16
#define HD 128
#define N1 6144   // NH * 3 * HD

typedef __attribute__((ext_vector_type(8))) short short8;
typedef __attribute__((ext_vector_type(4))) short short4v;
typedef __attribute__((ext_vector_type(8))) __bf16 bf16x8;
typedef __attribute__((ext_vector_type(4))) float f32x4;

__device__ __forceinline__ short f2b(float f) {
  unsigned u = __builtin_bit_cast(unsigned, f);
  unsigned r = (u + 0x7FFFu + ((u >> 16) & 1u)) >> 16;
  return (short)(r & 0xFFFFu);
}
__device__ __forceinline__ float b2f(short s) {
  return __builtin_bit_cast(float, (unsigned)((unsigned short)s) << 16);
}

__device__ __forceinline__ f32x4 mfma16(short8 a, short8 b, f32x4 c) {
  return __builtin_amdgcn_mfma_f32_16x16x32_bf16(
      __builtin_bit_cast(bf16x8, a), __builtin_bit_cast(bf16x8, b), c, 0, 0, 0);
}

// async global->LDS, 16B per lane. LDS dest = wave-uniform base + lane*16.
__device__ __forceinline__ void gload16(const short* g, short* l) {
  __builtin_amdgcn_global_load_lds(
      (const __attribute__((address_space(1))) unsigned int*)g,
      (__attribute__((address_space(3))) unsigned int*)l, 16, 0, 0);
}

// ---------------- cast fp32 -> bf16 bits ----------------
__global__ __launch_bounds__(256) void cast_f32_bf16(const float* __restrict__ in,
                                                     short* __restrict__ out, int n) {
  int i = (blockIdx.x * 256 + threadIdx.x) * 8;
  if (i >= n) return;
  float4 a = *reinterpret_cast<const float4*>(in + i);
  float4 b = *reinterpret_cast<const float4*>(in + i + 4);
  short8 o;
  o[0] = f2b(a.x); o[1] = f2b(a.y); o[2] = f2b(a.z); o[3] = f2b(a.w);
  o[4] = f2b(b.x); o[5] = f2b(b.y); o[6] = f2b(b.z); o[7] = f2b(b.w);
  *reinterpret_cast<short8*>(out + i) = o;
}

// ---------------- transpose + cast: in fp32 [R][C] -> out bf16 [C][R] ----------------
__global__ __launch_bounds__(256) void tr_cast(const float* __restrict__ in,
                                               short* __restrict__ out, int R, int C) {
  __shared__ float t[32][33];
  int c0 = blockIdx.x * 32, r0 = blockIdx.y * 32;
  int tx = threadIdx.x, ty = threadIdx.y;  // (32, 8)
#pragma unroll
  for (int i = 0; i < 4; i++) t[ty + i * 8][tx] = in[(r0 + ty + i * 8) * C + c0 + tx];
  __syncthreads();
#pragma unroll
  for (int i = 0; i < 4; i++) out[(c0 + ty + i * 8) * R + r0 + tx] = f2b(t[tx][ty + i * 8]);
}

// ---------------- QKV GEMM with fused bias + RoPE + layout epilogue ----------------
// A bf16 [2048][2048], Bt bf16 [6144][2048]. Tile 128x128. Since 384 = 3*128, each
// n-tile is purely Q, K, or V of head h = nb/3 (part = nb%3).
// Q -> Qb [h][s][d] (rotary d<32, * 1/sqrt(128));  K -> Kb [h][s][d] (rotary);
// V -> Vt [h][d][s] (transposed store).
__global__ __launch_bounds__(256) void gemm_qkv(const short* __restrict__ A,
                                                const short* __restrict__ Bt,
                                                const float* __restrict__ bias,
                                                short* __restrict__ Qb,
                                                short* __restrict__ Kb,
                                                short* __restrict__ Vt) {
  __shared__ __attribute__((aligned(16))) short aT[128 * 32];
  __shared__ __attribute__((aligned(16))) short bT[128 * 32];
  const int K = HID;
  int tid = threadIdx.x;
  int wave = tid >> 6, lane = tid & 63;
  int lhi = lane >> 4, llo = lane & 15;
  int wr = wave >> 1, wc = wave & 1;
  int m0 = blockIdx.y * 128, n0 = blockIdx.x * 128;
  int lr = lane >> 2, lc = (lane & 3) * 8;

  f32x4 acc[4][4];
#pragma unroll
  for (int a = 0; a < 4; a++)
#pragma unroll
    for (int b = 0; b < 4; b++) acc[a][b] = (f32x4){0.f, 0.f, 0.f, 0.f};

  const short* Ab = A + (long)m0 * K;
  const short* Bb = Bt + (long)n0 * K;

  for (int k0 = 0; k0 < K; k0 += 32) {
#pragma unroll
    for (int it = 0; it < 2; it++) {
      int c = wave * 2 + it;
      int row = c * 16 + lr;
      gload16(Ab + (long)row * K + k0 + lc, &aT[c * 512]);
      gload16(Bb + (long)row * K + k0 + lc, &bT[c * 512]);
    }
    __syncthreads();
    short8 af[4], bf[4];
#pragma unroll
    for (int mi = 0; mi < 4; mi++)
      af[mi] = *(const short8*)&aT[(wr * 64 + mi * 16 + llo) * 32 + lhi * 8];
#pragma unroll
    for (int ni = 0; ni < 4; ni++)
      bf[ni] = *(const short8*)&bT[(wc * 64 + ni * 16 + llo) * 32 + lhi * 8];
#pragma unroll
    for (int mi = 0; mi < 4; mi++)
#pragma unroll
      for (int ni = 0; ni < 4; ni++) acc[mi][ni] = mfma16(af[mi], bf[ni], acc[mi][ni]);
    __syncthreads();
  }

  // ---- fused epilogue ----
  int nb = blockIdx.x;
  int h = nb / 3, part = nb - h * 3;  // 0:Q 1:K 2:V
  const float INVNORM = 0.08838834764831845f;

  // bias first (rotary mixes partner columns, both must be biased)
#pragma unroll
  for (int mi = 0; mi < 4; mi++)
#pragma unroll
    for (int ni = 0; ni < 4; ni++) {
      float bv = bias[n0 + wc * 64 + ni * 16 + llo];
#pragma unroll
      for (int r = 0; r < 4; r++) acc[mi][ni][r] += bv;
    }

  if (part == 2) {
    // V: transposed store, 4 consecutive s per fragment -> 8B store
#pragma unroll
    for (int mi = 0; mi < 4; mi++)
#pragma unroll
      for (int ni = 0; ni < 4; ni++) {
        int d = wc * 64 + ni * 16 + llo;
        int sb = m0 + wr * 64 + mi * 16 + lhi * 4;
        short4v o;
#pragma unroll
        for (int r = 0; r < 4; r++) o[r] = f2b(acc[mi][ni][r]);
        *(short4v*)&Vt[(long)(h * HD + d) * SEQ + sb] = o;
      }
  } else {
    if (wc == 0) {
      // rotary: d = ni*16 + llo for ni<2; lo=d<16 (ni=0), hi=d in 16..31 (ni=1)
      float inv_freq = exp2f(-(float)llo * 0.8304820237218407f);
#pragma unroll
      for (int mi = 0; mi < 4; mi++)
#pragma unroll
        for (int r = 0; r < 4; r++) {
          int s = m0 + wr * 64 + mi * 16 + lhi * 4 + r;
          float fr = (float)s * inv_freq;
          float c, sn;
          sincosf(fr, &sn, &c);
          float lo = acc[mi][0][r], hi = acc[mi][1][r];
          acc[mi][0][r] = lo * c - hi * sn;
          acc[mi][1][r] = hi * c + lo * sn;
        }
    }
    short* dst = (part == 0) ? Qb : Kb;
    float scale = (part == 0) ? INVNORM : 1.0f;
#pragma unroll
    for (int mi = 0; mi < 4; mi++)
#pragma unroll
      for (int ni = 0; ni < 4; ni++)
#pragma unroll
        for (int r = 0; r < 4; r++) {
          int s = m0 + wr * 64 + mi * 16 + lhi * 4 + r;
          int d = wc * 64 + ni * 16 + llo;
          dst[(long)(h * SEQ + s) * HD + d] = f2b(acc[mi][ni][r] * scale);
        }
  }
}

// ---------------- Out-proj GEMM, BM=64 (512 blocks -> 2/CU residency) ----------------
// C(MxN fp32) = A(MxK bf16) * Bt(NxK)^T + bias
__global__ __launch_bounds__(256) void gemm_out(const short* __restrict__ A,
                                                const short* __restrict__ Bt,
                                                const float* __restrict__ bias,
                                                float* __restrict__ C,
                                                int M, int N, int K) {
  __shared__ __attribute__((aligned(16))) short aT[64 * 32];
  __shared__ __attribute__((aligned(16))) short bT[128 * 32];
  int tid = threadIdx.x;
  int wave = tid >> 6, lane = tid & 63;
  int lhi = lane >> 4, llo = lane & 15;
  int wr = wave >> 1, wc = wave & 1;
  int m0 = blockIdx.y * 64, n0 = blockIdx.x * 128;
  int lr = lane >> 2, lc = (lane & 3) * 8;

  f32x4 acc[2][4];
#pragma unroll
  for (int a = 0; a < 2; a++)
#pragma unroll
    for (int b = 0; b < 4; b++) acc[a][b] = (f32x4){0.f, 0.f, 0.f, 0.f};

  const short* Ab = A + (long)m0 * K;
  const short* Bb = Bt + (long)n0 * K;

  for (int k0 = 0; k0 < K; k0 += 32) {
    // A: 4 chunks of 16 rows, one per wave
    gload16(Ab + (long)(wave * 16 + lr) * K + k0 + lc, &aT[wave * 512]);
    // B: 8 chunks, two per wave
#pragma unroll
    for (int it = 0; it < 2; it++) {
      int c = wave * 2 + it;
      gload16(Bb + (long)(c * 16 + lr) * K + k0 + lc, &bT[c * 512]);
    }
    __syncthreads();
    short8 af[2], bf[4];
#pragma unroll
    for (int mi = 0; mi < 2; mi++)
      af[mi] = *(const short8*)&aT[(wr * 32 + mi * 16 + llo) * 32 + lhi * 8];
#pragma unroll
    for (int ni = 0; ni < 4; ni++)
      bf[ni] = *(const short8*)&bT[(wc * 64 + ni * 16 + llo) * 32 + lhi * 8];
#pragma unroll
    for (int mi = 0; mi < 2; mi++)
#pragma unroll
      for (int ni = 0; ni < 4; ni++) acc[mi][ni] = mfma16(af[mi], bf[ni], acc[mi][ni]);
    __syncthreads();
  }
#pragma unroll
  for (int mi = 0; mi < 2; mi++)
#pragma unroll
    for (int ni = 0; ni < 4; ni++)
#pragma unroll
      for (int r = 0; r < 4; r++) {
        int row = m0 + wr * 32 + mi * 16 + lhi * 4 + r;
        int col = n0 + wc * 64 + ni * 16 + llo;
        C[row * (long)N + col] = acc[mi][ni][r] + bias[col];
      }
}

// ---------------- Flash attention, split-K (chunks of <=8 KV-tiles) ----------------
// grid 1280 x 256. Qb [h][s][d] (pre-scaled), Kb [h][s][d], Vt [h][d][s].
// Writes unnormalized partial O (bf16) + per-row (m,l) fp32.
__global__ __launch_bounds__(256) void attn_kernel(const short* __restrict__ Qb,
                                                   const short* __restrict__ Kb,
                                                   const short* __restrict__ Vt,
                                                   short* __restrict__ Opart,
                                                   float* __restrict__ ml) {
  __shared__ __attribute__((aligned(16))) short Kl[2][64 * 136];
  __shared__ __attribute__((aligned(16))) short Vl[2][128 * 72];
  __shared__ __attribute__((aligned(16))) short Pl[4][16 * 72];
  int bid = blockIdx.x;
  int x = bid & 7, j = bid >> 3;          // XCD co-location: 2 heads per XCD
  int h = (x << 1) | (j >= 80 ? 1 : 0);
  int c = (j >= 80 ? j - 80 : j);
  c = 79 - c;                              // heaviest chunks (qt=31) dispatch first
  int qt = 0;
  for (; qt < 32; qt++) {
    int nc = (qt >> 3) + 1;
    if (c < nc) break;
    c -= nc;
  }
  int ci = c;
  int kt0 = ci * 8;
  int kt1 = min(qt + 1, kt0 + 8);
  int slot = ((h * 32 + qt) << 2) + ci;

  int tid = threadIdx.x;
  int wave = tid >> 6, lane = tid & 63;
  int lhi = lane >> 4, llo = lane & 15;
  int qrow0 = qt * 64 + wave * 16;

  const short* Kh = Kb + (long)h * SEQ * HD;
  const short* Vh = Vt + (long)h * HD * SEQ;

  // Q fragments
  short8 qf[4];
  const short* Qbase = Qb + (long)(h * SEQ + qrow0 + llo) * HD;
#pragma unroll
  for (int sl = 0; sl < 4; sl++) qf[sl] = *(const short8*)(Qbase + sl * 32 + lhi * 8);

  f32x4 oacc[8];
#pragma unroll
  for (int cb = 0; cb < 8; cb++) oacc[cb] = (f32x4){0.f, 0.f, 0.f, 0.f};
  float m[4], l[4];
#pragma unroll
  for (int r = 0; r < 4; r++) { m[r] = -INFINITY; l[r] = 0.f; }

  // staging registers (T14: issue early, write late)
  short8 kreg[4], vreg[4];
#define ISSUE_KV(T)                                                                     \
  {                                                                                     \
    _Pragma("unroll") for (int i = 0; i < 4; i++) {                                     \
      int s = tid + i * 256;                                                            \
      kreg[i] = *(const short8*)(Kh + (long)((T) * 64 + (s >> 4)) * HD + (s & 15) * 8); \
      vreg[i] = *(const short8*)(Vh + (long)(s >> 3) * SEQ + (T) * 64 + (s & 7) * 8);   \
    }                                                                                   \
  }
#define WRITE_KV(BUF)                                                        \
  {                                                                          \
    _Pragma("unroll") for (int i = 0; i < 4; i++) {                          \
      int s = tid + i * 256;                                                 \
      *(short8*)&Kl[BUF][(s >> 4) * 136 + (s & 15) * 8] = kreg[i];           \
      *(short8*)&Vl[BUF][(s >> 3) * 72 + (s & 7) * 8] = vreg[i];             \
    }                                                                        \
  }

  ISSUE_KV(kt0);
  WRITE_KV(0);
  __syncthreads();

  int cur = 0;
  for (int t = kt0; t < kt1; t++) {
    bool pre = (t + 1 < kt1);
    if (pre) ISSUE_KV(t + 1);

    // ---- S = Q K^T from Kl[cur] ----
    f32x4 sfr[4];
#pragma unroll
    for (int kb = 0; kb < 4; kb++) {
      sfr[kb] = (f32x4){0.f, 0.f, 0.f, 0.f};
#pragma unroll
      for (int sl = 0; sl < 4; sl++) {
        short8 bk = *(const short8*)&Kl[cur][(kb * 16 + llo) * 136 + sl * 32 + lhi * 8];
        sfr[kb] = mfma16(qf[sl], bk, sfr[kb]);
      }
    }

    // causal mask only on the diagonal tile
    if (t == qt) {
#pragma unroll
      for (int kb = 0; kb < 4; kb++)
#pragma unroll
        for (int r = 0; r < 4; r++) {
          int kg = t * 64 + kb * 16 + llo;
          int qg = qrow0 + lhi * 4 + r;
          if (kg > qg) sfr[kb][r] = -1e30f;
        }
    }

    // ---- online softmax ----
    float tmax[4];
#pragma unroll
    for (int r = 0; r < 4; r++)
      tmax[r] = fmaxf(fmaxf(sfr[0][r], sfr[1][r]), fmaxf(sfr[2][r], sfr[3][r]));
#pragma unroll
    for (int r = 0; r < 4; r++)
#pragma unroll
      for (int msk = 1; msk < 16; msk <<= 1)
        tmax[r] = fmaxf(tmax[r], __shfl_xor(tmax[r], msk));

    // T13 defer-max
    float grow = fmaxf(fmaxf(tmax[0] - m[0], tmax[1] - m[1]),
                       fmaxf(tmax[2] - m[2], tmax[3] - m[3]));
    if (!__all(grow <= 8.0f)) {
#pragma unroll
      for (int r = 0; r < 4; r++) {
        float mn = fmaxf(m[r], tmax[r]);
        float alpha = __expf(m[r] - mn);
        m[r] = mn;
        l[r] *= alpha;
#pragma unroll
        for (int cb = 0; cb < 8; cb++) oacc[cb][r] *= alpha;
      }
    }

    float psum[4];
#pragma unroll
    for (int r = 0; r < 4; r++) psum[r] = 0.f;
#pragma unroll
    for (int kb = 0; kb < 4; kb++)
#pragma unroll
      for (int r = 0; r < 4; r++) {
        float p = __expf(sfr[kb][r] - m[r]);
        psum[r] += p;
        Pl[wave][(lhi * 4 + r) * 72 + kb * 16 + llo] = f2b(p);
      }
#pragma unroll
    for (int r = 0; r < 4; r++) {
#pragma unroll
      for (int msk = 1; msk < 16; msk <<= 1) psum[r] += __shfl_xor(psum[r], msk);
      l[r] += psum[r];
    }

    // ---- O += P @ V from Vl[cur] ----
#pragma unroll
    for (int ks = 0; ks < 2; ks++) {
      short8 pa = *(const short8*)&Pl[wave][llo * 72 + ks * 32 + lhi * 8];
#pragma unroll
      for (int cb = 0; cb < 8; cb++) {
        short8 bv = *(const short8*)&Vl[cur][(cb * 16 + llo) * 72 + ks * 32 + lhi * 8];
        oacc[cb] = mfma16(pa, bv, oacc[cb]);
      }
    }

    if (pre) {
      WRITE_KV(cur ^ 1);
      __syncthreads();
      cur ^= 1;
    }
  }
#undef ISSUE_KV
#undef WRITE_KV

  // epilogue: write unnormalized partial O (bf16) + m,l (fp32)
  long obase = (long)slot * (64 * 128);
#pragma unroll
  for (int cb = 0; cb < 8; cb++)
#pragma unroll
    for (int r = 0; r < 4; r++) {
      int row = wave * 16 + lhi * 4 + r;
      Opart[obase + row * 128 + cb * 16 + llo] = f2b(oacc[cb][r]);
    }
  if (llo == 0) {
#pragma unroll
    for (int r = 0; r < 4; r++) {
      int row = wave * 16 + lhi * 4 + r;
      ml[slot * 128 + row * 2 + 0] = m[r];
      ml[slot * 128 + row * 2 + 1] = l[r];
    }
  }
}

// ---------------- merge split-K partials -> attn bf16 [s][h*128+d] ----------------
// grid (32, 16) = (qt, h), block 256
__global__ __launch_bounds__(256) void attn_merge(const short* __restrict__ Opart,
                                                  const float* __restrict__ ml,
                                                  short* __restrict__ out) {
  int qt = blockIdx.x, h = blockIdx.y;
  int nc = (qt >> 3) + 1;
  int tid = threadIdx.x;
  int row = tid >> 2;          // 0..63
  int c0 = (tid & 3) * 32;     // col base, 32 cols/thread
  int slot0 = (h * 32 + qt) << 2;

  float mm[4], ll[4], alpha[4];
  float M = -INFINITY;
  for (int i = 0; i < nc; i++) {
    mm[i] = ml[(slot0 + i) * 128 + row * 2 + 0];
    ll[i] = ml[(slot0 + i) * 128 + row * 2 + 1];
    M = fmaxf(M, mm[i]);
  }
  float L = 0.f;
  for (int i = 0; i < nc; i++) {
    alpha[i] = __expf(mm[i] - M);
    L += ll[i] * alpha[i];
  }
  float invL = 1.0f / L;

  int s = qt * 64 + row;
#pragma unroll
  for (int cc = 0; cc < 32; cc += 8) {
    float acc[8];
#pragma unroll
    for (int jj = 0; jj < 8; jj++) acc[jj] = 0.f;
    for (int i = 0; i < nc; i++) {
      short8 v = *(const short8*)&Opart[(long)(slot0 + i) * 8192 + row * 128 + c0 + cc];
#pragma unroll
      for (int jj = 0; jj < 8; jj++) acc[jj] += alpha[i] * b2f(v[jj]);
    }
    short8 o;
#pragma unroll
    for (int jj = 0; jj < 8; jj++) o[jj] = f2b(acc[jj] * invL);
    *(short8*)&out[s * HID + h * HD + c0 + cc] = o;
  }
}

extern "C" void kernel_launch(void* const* d_in, const int* in_sizes, int n_in,
                              void* d_out, int out_size, void* d_ws, size_t ws_size,
                              hipStream_t stream) {
  (void)in_sizes; (void)n_in; (void)out_size; (void)ws_size;
  const float* hs = (const float*)d_in[0];
  // d_in[1] = attention_mask (tril causal) — enforced structurally
  const float* w1 = (const float*)d_in[2];
  const float* b1 = (const float*)d_in[3];
  const float* w2 = (const float*)d_in[4];
  const float* b2 = (const float*)d_in[5];
  float* out = (float*)d_out;
  char* ws = (char*)d_ws;

  // Opart (32MB) overlays hsb+w1t — both dead after gemm_qkv (stream-ordered).
  short* hsb   = (short*)(ws);                 // [0,8) MB
  short* w1t   = (short*)(ws + (8L << 20));    // [8,32) MB
  short* Opart = (short*)(ws);                 // [0,32) MB (after gemm_qkv)
  short* w2t   = (short*)(ws + (32L << 20));   // [32,40) MB
  short* Qb    = (short*)(ws + (64L << 20));   // [64,72) MB
  short* Kb    = (short*)(ws + (72L << 20));   // [72,80) MB
  short* Vt    = (short*)(ws + (80L << 20));   // [80,88) MB
  short* attnb = (short*)(ws + (88L << 20));   // [88,96) MB
  float* ml    = (float*)(ws + (96L << 20));   // [96,97) MB

  cast_f32_bf16<<<(SEQ * HID) / 2048, 256, 0, stream>>>(hs, hsb, SEQ * HID);
  tr_cast<<<dim3(N1 / 32, HID / 32), dim3(32, 8), 0, stream>>>(w1, w1t, HID, N1);
  tr_cast<<<dim3(HID / 32, HID / 32), dim3(32, 8), 0, stream>>>(w2, w2t, HID, HID);
  gemm_qkv<<<dim3(N1 / 128, SEQ / 128), 256, 0, stream>>>(hsb, w1t, b1, Qb, Kb, Vt);
  attn_kernel<<<1280, 256, 0, stream>>>(Qb, Kb, Vt, Opart, ml);
  attn_merge<<<dim3(32, 16), 256, 0, stream>>>(Opart, ml, attnb);
  gemm_out<<<dim3(HID / 128, SEQ / 64), 256, 0, stream>>>(attnb, w2t, b2, out, SEQ, HID, HID);
}

// Round 7
// 332.404 us; speedup vs baseline: 1.4997x; 1.0006x over previous
//
#include <hip/hip_runtime.h>

#define SEQ 2048
#define HID 2048
#define NH 16
#define HD 128
#define N1 6144   // NH * 3 * HD

typedef __attribute__((ext_vector_type(8))) short short8;
typedef __attribute__((ext_vector_type(8))) __bf16 bf16x8;
typedef __attribute__((ext_vector_type(4))) float f32x4;

__device__ __forceinline__ short f2b(float f) {
  unsigned u = __builtin_bit_cast(unsigned, f);
  unsigned r = (u + 0x7FFFu + ((u >> 16) & 1u)) >> 16;
  return (short)(r & 0xFFFFu);
}
__device__ __forceinline__ float b2f(short s) {
  return __builtin_bit_cast(float, (unsigned)((unsigned short)s) << 16);
}

__device__ __forceinline__ f32x4 mfma16(short8 a, short8 b, f32x4 c) {
  return __builtin_amdgcn_mfma_f32_16x16x32_bf16(
      __builtin_bit_cast(bf16x8, a), __builtin_bit_cast(bf16x8, b), c, 0, 0, 0);
}

// async global->LDS, 16B per lane. LDS dest = wave-uniform base + lane*16.
__device__ __forceinline__ void gload16(const short* g, short* l) {
  __builtin_amdgcn_global_load_lds(
      (const __attribute__((address_space(1))) unsigned int*)g,
      (__attribute__((address_space(3))) unsigned int*)l, 16, 0, 0);
}

// ---------------- cast fp32 -> bf16 bits ----------------
__global__ __launch_bounds__(256) void cast_f32_bf16(const float* __restrict__ in,
                                                     short* __restrict__ out, int n) {
  int i = (blockIdx.x * 256 + threadIdx.x) * 8;
  if (i >= n) return;
  float4 a = *reinterpret_cast<const float4*>(in + i);
  float4 b = *reinterpret_cast<const float4*>(in + i + 4);
  short8 o;
  o[0] = f2b(a.x); o[1] = f2b(a.y); o[2] = f2b(a.z); o[3] = f2b(a.w);
  o[4] = f2b(b.x); o[5] = f2b(b.y); o[6] = f2b(b.z); o[7] = f2b(b.w);
  *reinterpret_cast<short8*>(out + i) = o;
}

// ---------------- transpose + cast: in fp32 [R][C] -> out bf16 [C][R] ----------------
__global__ __launch_bounds__(256) void tr_cast(const float* __restrict__ in,
                                               short* __restrict__ out, int R, int C) {
  __shared__ float t[32][33];
  int c0 = blockIdx.x * 32, r0 = blockIdx.y * 32;
  int tx = threadIdx.x, ty = threadIdx.y;  // (32, 8)
#pragma unroll
  for (int i = 0; i < 4; i++) t[ty + i * 8][tx] = in[(r0 + ty + i * 8) * C + c0 + tx];
  __syncthreads();
#pragma unroll
  for (int i = 0; i < 4; i++) out[(c0 + ty + i * 8) * R + r0 + tx] = f2b(t[tx][ty + i * 8]);
}

// ---------------- GEMM (m97 structure, proven): C = A * Bt^T + bias ----------------
// 1D grid (nbx * nby blocks), XCD-swizzled: grid must be divisible by 8.
// BF16OUT=1 -> bf16 output, else fp32.
template <int BF16OUT>
__global__ __launch_bounds__(256) void gemm_bt(const short* __restrict__ A,
                                               const short* __restrict__ Bt,
                                               const float* __restrict__ bias,
                                               void* __restrict__ Cv,
                                               int M, int N, int K, int nbx) {
  __shared__ __attribute__((aligned(16))) short aT[128 * 32];
  __shared__ __attribute__((aligned(16))) short bT[128 * 32];
  int tid = threadIdx.x;
  int wave = tid >> 6, lane = tid & 63;
  int lhi = lane >> 4, llo = lane & 15;
  int wr = wave >> 1, wc = wave & 1;

  // T1 XCD swizzle (bijective: gridDim.x % 8 == 0). Consecutive swz share the
  // A-panel (mb) within an XCD -> L2 reuse.
  int cpx = gridDim.x >> 3;
  int bid = blockIdx.x;
  int swz = (bid & 7) * cpx + (bid >> 3);
  int nb = swz % nbx, mb = swz / nbx;
  int m0 = mb * 128, n0 = nb * 128;
  int lr = lane >> 2, lc = (lane & 3) * 8;  // staging: lane's row-in-chunk / col

  f32x4 acc[4][4];
#pragma unroll
  for (int a = 0; a < 4; a++)
#pragma unroll
    for (int b = 0; b < 4; b++) acc[a][b] = (f32x4){0.f, 0.f, 0.f, 0.f};

  const short* Ab = A + (long)m0 * K;
  const short* Bb = Bt + (long)n0 * K;

  for (int k0 = 0; k0 < K; k0 += 32) {
#pragma unroll
    for (int it = 0; it < 2; it++) {
      int c = wave * 2 + it;  // chunk 0..7, 16 rows each
      int row = c * 16 + lr;
      gload16(Ab + (long)row * K + k0 + lc, &aT[c * 512]);
      gload16(Bb + (long)row * K + k0 + lc, &bT[c * 512]);
    }
    __syncthreads();
    short8 af[4], bf[4];
#pragma unroll
    for (int mi = 0; mi < 4; mi++)
      af[mi] = *(const short8*)&aT[(wr * 64 + mi * 16 + llo) * 32 + lhi * 8];
#pragma unroll
    for (int ni = 0; ni < 4; ni++)
      bf[ni] = *(const short8*)&bT[(wc * 64 + ni * 16 + llo) * 32 + lhi * 8];
#pragma unroll
    for (int mi = 0; mi < 4; mi++)
#pragma unroll
      for (int ni = 0; ni < 4; ni++) acc[mi][ni] = mfma16(af[mi], bf[ni], acc[mi][ni]);
    __syncthreads();
  }
#pragma unroll
  for (int mi = 0; mi < 4; mi++)
#pragma unroll
    for (int ni = 0; ni < 4; ni++)
#pragma unroll
      for (int r = 0; r < 4; r++) {
        int row = m0 + wr * 64 + mi * 16 + lhi * 4 + r;
        int col = n0 + wc * 64 + ni * 16 + llo;
        float v = acc[mi][ni][r] + bias[col];
        if (BF16OUT)
          ((short*)Cv)[row * (long)N + col] = f2b(v);
        else
          ((float*)Cv)[row * (long)N + col] = v;
      }
}

// ---------------- Fused RoPE(Q,K) + V transpose (proven R4 version) ----------------
// qkv bf16 [s][h*384+e] -> Qb/Kb bf16 [h][s][d] (Q pre-scaled), Vt bf16 [h][d][s]
__global__ __launch_bounds__(256) void rope_v(const short* __restrict__ qkv,
                                              short* __restrict__ Qb,
                                              short* __restrict__ Kb,
                                              short* __restrict__ Vt) {
  __shared__ short t[32][33];
  const float INVNORM = 0.08838834764831845f;  // 1/sqrt(128)
  int d0 = blockIdx.x * 32, s0 = blockIdx.y * 32, h = blockIdx.z;
  int tx = threadIdx.x, ty = threadIdx.y;  // (32, 8)
#pragma unroll
  for (int i = 0; i < 4; i++) {
    int s = s0 + ty + i * 8;
    int base = s * N1 + h * 384;
    t[ty + i * 8][tx] = qkv[base + 256 + d0 + tx];
    float q = b2f(qkv[base + d0 + tx]);
    float k = b2f(qkv[base + 128 + d0 + tx]);
    if (d0 == 0) {
      float qo = __shfl_xor(q, 16);
      float ko = __shfl_xor(k, 16);
      int ii = tx & 15;
      float inv_freq = exp2f(-(float)ii * 0.8304820237218407f);
      float fr = (float)s * inv_freq;
      float c, sn;
      sincosf(fr, &sn, &c);
      float sgn = (tx < 16) ? -1.f : 1.f;
      q = q * c + sgn * qo * sn;
      k = k * c + sgn * ko * sn;
    }
    int o = (h * SEQ + s) * HD + d0 + tx;
    Qb[o] = f2b(q * INVNORM);
    Kb[o] = f2b(k);
  }
  __syncthreads();
#pragma unroll
  for (int i = 0; i < 4; i++)
    Vt[(h * HD + d0 + ty + i * 8) * SEQ + s0 + tx] = t[tx][ty + i * 8];
}

// ---------------- Out-proj GEMM, BM=64 (512 blocks), XCD-swizzled ----------------
__global__ __launch_bounds__(256) void gemm_out(const short* __restrict__ A,
                                                const short* __restrict__ Bt,
                                                const float* __restrict__ bias,
                                                float* __restrict__ C,
                                                int M, int N, int K, int nbx) {
  __shared__ __attribute__((aligned(16))) short aT[64 * 32];
  __shared__ __attribute__((aligned(16))) short bT[128 * 32];
  int tid = threadIdx.x;
  int wave = tid >> 6, lane = tid & 63;
  int lhi = lane >> 4, llo = lane & 15;
  int wr = wave >> 1, wc = wave & 1;

  int cpx = gridDim.x >> 3;
  int bid = blockIdx.x;
  int swz = (bid & 7) * cpx + (bid >> 3);
  int nb = swz % nbx, mb = swz / nbx;
  int m0 = mb * 64, n0 = nb * 128;
  int lr = lane >> 2, lc = (lane & 3) * 8;

  f32x4 acc[2][4];
#pragma unroll
  for (int a = 0; a < 2; a++)
#pragma unroll
    for (int b = 0; b < 4; b++) acc[a][b] = (f32x4){0.f, 0.f, 0.f, 0.f};

  const short* Ab = A + (long)m0 * K;
  const short* Bb = Bt + (long)n0 * K;

  for (int k0 = 0; k0 < K; k0 += 32) {
    gload16(Ab + (long)(wave * 16 + lr) * K + k0 + lc, &aT[wave * 512]);
#pragma unroll
    for (int it = 0; it < 2; it++) {
      int c = wave * 2 + it;
      gload16(Bb + (long)(c * 16 + lr) * K + k0 + lc, &bT[c * 512]);
    }
    __syncthreads();
    short8 af[2], bf[4];
#pragma unroll
    for (int mi = 0; mi < 2; mi++)
      af[mi] = *(const short8*)&aT[(wr * 32 + mi * 16 + llo) * 32 + lhi * 8];
#pragma unroll
    for (int ni = 0; ni < 4; ni++)
      bf[ni] = *(const short8*)&bT[(wc * 64 + ni * 16 + llo) * 32 + lhi * 8];
#pragma unroll
    for (int mi = 0; mi < 2; mi++)
#pragma unroll
      for (int ni = 0; ni < 4; ni++) acc[mi][ni] = mfma16(af[mi], bf[ni], acc[mi][ni]);
    __syncthreads();
  }
#pragma unroll
  for (int mi = 0; mi < 2; mi++)
#pragma unroll
    for (int ni = 0; ni < 4; ni++)
#pragma unroll
      for (int r = 0; r < 4; r++) {
        int row = m0 + wr * 32 + mi * 16 + lhi * 4 + r;
        int col = n0 + wc * 64 + ni * 16 + llo;
        C[row * (long)N + col] = acc[mi][ni][r] + bias[col];
      }
}

// ---------------- Flash attention, split-K (chunks of <=8 KV-tiles) ----------------
__global__ __launch_bounds__(256) void attn_kernel(const short* __restrict__ Qb,
                                                   const short* __restrict__ Kb,
                                                   const short* __restrict__ Vt,
                                                   short* __restrict__ Opart,
                                                   float* __restrict__ ml) {
  __shared__ __attribute__((aligned(16))) short Kl[2][64 * 136];
  __shared__ __attribute__((aligned(16))) short Vl[2][128 * 72];
  __shared__ __attribute__((aligned(16))) short Pl[4][16 * 72];
  int bid = blockIdx.x;
  int x = bid & 7, j = bid >> 3;
  int h = (x << 1) | (j >= 80 ? 1 : 0);
  int c = (j >= 80 ? j - 80 : j);
  c = 79 - c;
  int qt = 0;
  for (; qt < 32; qt++) {
    int nc = (qt >> 3) + 1;
    if (c < nc) break;
    c -= nc;
  }
  int ci = c;
  int kt0 = ci * 8;
  int kt1 = min(qt + 1, kt0 + 8);
  int slot = ((h * 32 + qt) << 2) + ci;

  int tid = threadIdx.x;
  int wave = tid >> 6, lane = tid & 63;
  int lhi = lane >> 4, llo = lane & 15;
  int qrow0 = qt * 64 + wave * 16;

  const short* Kh = Kb + (long)h * SEQ * HD;
  const short* Vh = Vt + (long)h * HD * SEQ;

  short8 qf[4];
  const short* Qbase = Qb + (long)(h * SEQ + qrow0 + llo) * HD;
#pragma unroll
  for (int sl = 0; sl < 4; sl++) qf[sl] = *(const short8*)(Qbase + sl * 32 + lhi * 8);

  f32x4 oacc[8];
#pragma unroll
  for (int cb = 0; cb < 8; cb++) oacc[cb] = (f32x4){0.f, 0.f, 0.f, 0.f};
  float m[4], l[4];
#pragma unroll
  for (int r = 0; r < 4; r++) { m[r] = -INFINITY; l[r] = 0.f; }

  short8 kreg[4], vreg[4];
#define ISSUE_KV(T)                                                                     \
  {                                                                                     \
    _Pragma("unroll") for (int i = 0; i < 4; i++) {                                     \
      int s = tid + i * 256;                                                            \
      kreg[i] = *(const short8*)(Kh + (long)((T) * 64 + (s >> 4)) * HD + (s & 15) * 8); \
      vreg[i] = *(const short8*)(Vh + (long)(s >> 3) * SEQ + (T) * 64 + (s & 7) * 8);   \
    }                                                                                   \
  }
#define WRITE_KV(BUF)                                                        \
  {                                                                          \
    _Pragma("unroll") for (int i = 0; i < 4; i++) {                          \
      int s = tid + i * 256;                                                 \
      *(short8*)&Kl[BUF][(s >> 4) * 136 + (s & 15) * 8] = kreg[i];           \
      *(short8*)&Vl[BUF][(s >> 3) * 72 + (s & 7) * 8] = vreg[i];             \
    }                                                                        \
  }

  ISSUE_KV(kt0);
  WRITE_KV(0);
  __syncthreads();

  int cur = 0;
  for (int t = kt0; t < kt1; t++) {
    bool pre = (t + 1 < kt1);
    if (pre) ISSUE_KV(t + 1);

    f32x4 sfr[4];
#pragma unroll
    for (int kb = 0; kb < 4; kb++) {
      sfr[kb] = (f32x4){0.f, 0.f, 0.f, 0.f};
#pragma unroll
      for (int sl = 0; sl < 4; sl++) {
        short8 bk = *(const short8*)&Kl[cur][(kb * 16 + llo) * 136 + sl * 32 + lhi * 8];
        sfr[kb] = mfma16(qf[sl], bk, sfr[kb]);
      }
    }

    if (t == qt) {
#pragma unroll
      for (int kb = 0; kb < 4; kb++)
#pragma unroll
        for (int r = 0; r < 4; r++) {
          int kg = t * 64 + kb * 16 + llo;
          int qg = qrow0 + lhi * 4 + r;
          if (kg > qg) sfr[kb][r] = -1e30f;
        }
    }

    float tmax[4];
#pragma unroll
    for (int r = 0; r < 4; r++)
      tmax[r] = fmaxf(fmaxf(sfr[0][r], sfr[1][r]), fmaxf(sfr[2][r], sfr[3][r]));
#pragma unroll
    for (int r = 0; r < 4; r++)
#pragma unroll
      for (int msk = 1; msk < 16; msk <<= 1)
        tmax[r] = fmaxf(tmax[r], __shfl_xor(tmax[r], msk));

    float grow = fmaxf(fmaxf(tmax[0] - m[0], tmax[1] - m[1]),
                       fmaxf(tmax[2] - m[2], tmax[3] - m[3]));
    if (!__all(grow <= 8.0f)) {
#pragma unroll
      for (int r = 0; r < 4; r++) {
        float mn = fmaxf(m[r], tmax[r]);
        float alpha = __expf(m[r] - mn);
        m[r] = mn;
        l[r] *= alpha;
#pragma unroll
        for (int cb = 0; cb < 8; cb++) oacc[cb][r] *= alpha;
      }
    }

    float psum[4];
#pragma unroll
    for (int r = 0; r < 4; r++) psum[r] = 0.f;
#pragma unroll
    for (int kb = 0; kb < 4; kb++)
#pragma unroll
      for (int r = 0; r < 4; r++) {
        float p = __expf(sfr[kb][r] - m[r]);
        psum[r] += p;
        Pl[wave][(lhi * 4 + r) * 72 + kb * 16 + llo] = f2b(p);
      }
#pragma unroll
    for (int r = 0; r < 4; r++) {
#pragma unroll
      for (int msk = 1; msk < 16; msk <<= 1) psum[r] += __shfl_xor(psum[r], msk);
      l[r] += psum[r];
    }

#pragma unroll
    for (int ks = 0; ks < 2; ks++) {
      short8 pa = *(const short8*)&Pl[wave][llo * 72 + ks * 32 + lhi * 8];
#pragma unroll
      for (int cb = 0; cb < 8; cb++) {
        short8 bv = *(const short8*)&Vl[cur][(cb * 16 + llo) * 72 + ks * 32 + lhi * 8];
        oacc[cb] = mfma16(pa, bv, oacc[cb]);
      }
    }

    if (pre) {
      WRITE_KV(cur ^ 1);
      __syncthreads();
      cur ^= 1;
    }
  }
#undef ISSUE_KV
#undef WRITE_KV

  long obase = (long)slot * (64 * 128);
#pragma unroll
  for (int cb = 0; cb < 8; cb++)
#pragma unroll
    for (int r = 0; r < 4; r++) {
      int row = wave * 16 + lhi * 4 + r;
      Opart[obase + row * 128 + cb * 16 + llo] = f2b(oacc[cb][r]);
    }
  if (llo == 0) {
#pragma unroll
    for (int r = 0; r < 4; r++) {
      int row = wave * 16 + lhi * 4 + r;
      ml[slot * 128 + row * 2 + 0] = m[r];
      ml[slot * 128 + row * 2 + 1] = l[r];
    }
  }
}

// ---------------- merge split-K partials -> attn bf16 [s][h*128+d] ----------------
__global__ __launch_bounds__(256) void attn_merge(const short* __restrict__ Opart,
                                                  const float* __restrict__ ml,
                                                  short* __restrict__ out) {
  int qt = blockIdx.x, h = blockIdx.y;
  int nc = (qt >> 3) + 1;
  int tid = threadIdx.x;
  int row = tid >> 2;
  int c0 = (tid & 3) * 32;
  int slot0 = (h * 32 + qt) << 2;

  float mm[4], ll[4], alpha[4];
  float M = -INFINITY;
  for (int i = 0; i < nc; i++) {
    mm[i] = ml[(slot0 + i) * 128 + row * 2 + 0];
    ll[i] = ml[(slot0 + i) * 128 + row * 2 + 1];
    M = fmaxf(M, mm[i]);
  }
  float L = 0.f;
  for (int i = 0; i < nc; i++) {
    alpha[i] = __expf(mm[i] - M);
    L += ll[i] * alpha[i];
  }
  float invL = 1.0f / L;

  int s = qt * 64 + row;
#pragma unroll
  for (int cc = 0; cc < 32; cc += 8) {
    float acc[8];
#pragma unroll
    for (int jj = 0; jj < 8; jj++) acc[jj] = 0.f;
    for (int i = 0; i < nc; i++) {
      short8 v = *(const short8*)&Opart[(long)(slot0 + i) * 8192 + row * 128 + c0 + cc];
#pragma unroll
      for (int jj = 0; jj < 8; jj++) acc[jj] += alpha[i] * b2f(v[jj]);
    }
    short8 o;
#pragma unroll
    for (int jj = 0; jj < 8; jj++) o[jj] = f2b(acc[jj] * invL);
    *(short8*)&out[s * HID + h * HD + c0 + cc] = o;
  }
}

extern "C" void kernel_launch(void* const* d_in, const int* in_sizes, int n_in,
                              void* d_out, int out_size, void* d_ws, size_t ws_size,
                              hipStream_t stream) {
  (void)in_sizes; (void)n_in; (void)out_size; (void)ws_size;
  const float* hs = (const float*)d_in[0];
  // d_in[1] = attention_mask (tril causal) — enforced structurally
  const float* w1 = (const float*)d_in[2];
  const float* b1 = (const float*)d_in[3];
  const float* w2 = (const float*)d_in[4];
  const float* b2 = (const float*)d_in[5];
  float* out = (float*)d_out;
  char* ws = (char*)d_ws;

  // Opart (32MB) overlays hsb+w1t — both dead after the QKV GEMM (stream-ordered).
  short* hsb   = (short*)(ws);                 // [0,8) MB
  short* w1t   = (short*)(ws + (8L << 20));    // [8,32) MB
  short* Opart = (short*)(ws);                 // [0,32) MB (after QKV GEMM)
  short* w2t   = (short*)(ws + (32L << 20));   // [32,40) MB
  short* qkvb  = (short*)(ws + (40L << 20));   // [40,64) MB
  short* Qb    = (short*)(ws + (64L << 20));   // [64,72) MB
  short* Kb    = (short*)(ws + (72L << 20));   // [72,80) MB
  short* Vt    = (short*)(ws + (80L << 20));   // [80,88) MB
  short* attnb = (short*)(ws + (88L << 20));   // [88,96) MB
  float* ml    = (float*)(ws + (96L << 20));   // [96,97) MB

  cast_f32_bf16<<<(SEQ * HID) / 2048, 256, 0, stream>>>(hs, hsb, SEQ * HID);
  tr_cast<<<dim3(N1 / 32, HID / 32), dim3(32, 8), 0, stream>>>(w1, w1t, HID, N1);
  tr_cast<<<dim3(HID / 32, HID / 32), dim3(32, 8), 0, stream>>>(w2, w2t, HID, HID);
  // QKV GEMM: 48 x 16 = 768 blocks (768 % 8 == 0 -> bijective XCD swizzle)
  gemm_bt<1><<<768, 256, 0, stream>>>(hsb, w1t, b1, qkvb, SEQ, N1, HID, N1 / 128);
  rope_v<<<dim3(HD / 32, SEQ / 32, NH), dim3(32, 8), 0, stream>>>(qkvb, Qb, Kb, Vt);
  attn_kernel<<<1280, 256, 0, stream>>>(Qb, Kb, Vt, Opart, ml);
  attn_merge<<<dim3(32, 16), 256, 0, stream>>>(Opart, ml, attnb);
  // Out GEMM: 16 x 32 = 512 blocks (512 % 8 == 0)
  gemm_out<<<512, 256, 0, stream>>>(attnb, w2t, b2, out, SEQ, HID, HID, HID / 128);
}